// Round 5
// baseline (948.935 us; speedup 1.0000x reference)
//
#include <hip/hip_runtime.h>
#include <stdint.h>

// ---------------- problem constants ----------------
constexpr int CB = 8, CC = 4, CN = 2048, CE = 512, CF = 2048;
constexpr long long TOT = (long long)CB * CC * CN * CE;
constexpr int GRP = 16;       // attention batches per LLC-resident group
constexpr int MCH = 65536;    // FFN rows (single chunk)
constexpr float SCALE = 0.04419417382415922f;  // 1/sqrt(512)
constexpr float MASK_SCALE = 5.0f;
constexpr float EPS = 1e-5f;

typedef unsigned short bf16_t;
typedef __attribute__((ext_vector_type(4))) float f32x4;
typedef __attribute__((ext_vector_type(8))) short s16x8;

#define DEV static __device__ __forceinline__

DEV unsigned short f2bf(float f) {
    unsigned u = __float_as_uint(f);
    unsigned r = (u + 0x7fffu + ((u >> 16) & 1u)) >> 16;
    return (unsigned short)r;
}
DEV float bf2f(unsigned short b) {
    return __uint_as_float(((unsigned)b) << 16);
}

typedef const __attribute__((address_space(1))) unsigned int* gptr_t;
typedef __attribute__((address_space(3))) unsigned int* lptr_t;
DEV void async16(const void* g, void* l) {
    __builtin_amdgcn_global_load_lds((gptr_t)g, (lptr_t)l, 16, 0, 0);
}

#define FULL_BAR() do { asm volatile("" ::: "memory"); __builtin_amdgcn_s_barrier(); asm volatile("" ::: "memory"); } while (0)
#define LGKM0() asm volatile("s_waitcnt lgkmcnt(0)" ::: "memory")

// ---------------- reductions (256-thread blocks = 4 waves) ----------------
DEV float blockSum256(float v, float* sm) {
    #pragma unroll
    for (int o = 32; o; o >>= 1) v += __shfl_xor(v, o);
    int w = threadIdx.x >> 6;
    __syncthreads();
    if ((threadIdx.x & 63) == 0) sm[w] = v;
    __syncthreads();
    return sm[0] + sm[1] + sm[2] + sm[3];
}
DEV float blockMax256(float v, float* sm) {
    #pragma unroll
    for (int o = 32; o; o >>= 1) v = fmaxf(v, __shfl_xor(v, o));
    int w = threadIdx.x >> 6;
    __syncthreads();
    if ((threadIdx.x & 63) == 0) sm[w] = v;
    __syncthreads();
    return fmaxf(fmaxf(sm[0], sm[1]), fmaxf(sm[2], sm[3]));
}

// ---------------- fp32 -> bf16 convert ----------------
__global__ __launch_bounds__(256) void cvt_f32_bf16_vec(
    const float* __restrict__ in, bf16_t* __restrict__ out, long long n) {
    long long i = ((long long)blockIdx.x * 256 + threadIdx.x) * 4;
    long long stride = (long long)gridDim.x * 1024;
    for (; i < n; i += stride) {
        float4 v = *reinterpret_cast<const float4*>(in + i);
        ushort4 u;
        u.x = f2bf(v.x); u.y = f2bf(v.y); u.z = f2bf(v.z); u.w = f2bf(v.w);
        *reinterpret_cast<ushort4*>(out + i) = u;
    }
}

// ---------------- transpose fp32[R][C] -> bf16[C][R] (weights) ----------------
__global__ __launch_bounds__(256) void transpose_f32_bf16(
    const float* __restrict__ in, bf16_t* __restrict__ out,
    int R, int Cc) {
    __shared__ float tile[32][33];
    int rb = blockIdx.y * 32, cb = blockIdx.x * 32;
    int tx = threadIdx.x & 31, ty = threadIdx.x >> 5;
    #pragma unroll
    for (int i = 0; i < 32; i += 8)
        tile[ty + i][tx] = in[(size_t)(rb + ty + i) * Cc + cb + tx];
    __syncthreads();
    #pragma unroll
    for (int i = 0; i < 32; i += 8)
        out[(size_t)(cb + ty + i) * R + rb + tx] = f2bf(tile[tx][ty + i]);
}

// ---------------- transpose bf16[R][C] -> bf16[C][R], batched via z ----------------
__global__ __launch_bounds__(256) void transpose_bf16(
    const bf16_t* __restrict__ in, bf16_t* __restrict__ out,
    int R, int Cc, long long sIn, long long sOut) {
    __shared__ bf16_t tile[32][36];
    const bf16_t* inz = in + (size_t)blockIdx.z * sIn;
    bf16_t* outz = out + (size_t)blockIdx.z * sOut;
    int rb = blockIdx.y * 32, cb = blockIdx.x * 32;
    int t = threadIdx.x;
    int r = t >> 3, c4 = (t & 7) * 4;
    *(ushort4*)&tile[r][c4] = *(const ushort4*)&inz[(size_t)(rb + r) * Cc + cb + c4];
    __syncthreads();
    int c = t >> 3, r4 = (t & 7) * 4;
    ushort4 w;
    w.x = tile[r4 + 0][c]; w.y = tile[r4 + 1][c];
    w.z = tile[r4 + 2][c]; w.w = tile[r4 + 3][c];
    *(ushort4*)&outz[(size_t)(cb + c) * R + rb + r4] = w;
}

// ============ 256x256 GEMM: C[M,Nc] = A[M,K] @ B[Nc,K]^T ============
// bf16 in, fp32 acc. 8 waves (2Mx4N), BK=64, 128KiB dyn LDS double-buffered.
// 2 phases / K-tile, 1 barrier per phase, counted vmcnt (never 0 mid-loop).
// LDS-transposed coalesced epilogue (bf16 EPIs): shfl col-pairing -> b32 LDS
// writes -> b128 reads -> dwordx4 global stores (full 64B lines).
// EPI 1: +bias relu bf16. 3: alpha*bf16. 4: +bias bf16.
template <int EPI>
__global__ __launch_bounds__(512, 2) void gemm256(
    const bf16_t* __restrict__ A, const bf16_t* __restrict__ B,
    void* __restrict__ Cptr, const float* __restrict__ bias, float alpha,
    int M, int Nc, int K, long long sA, long long sB, long long sC) {
    extern __shared__ bf16_t lds[];
    bf16_t* AsL = lds;           // [dbuf2][half2][128*64]
    bf16_t* BsL = lds + 32768;

    // ---- XCD-aware bijective swizzle (requires nwg % 8 == 0) ----
    int bx, by, bz;
    {
        int gx = gridDim.x, gy = gridDim.y;
        int nwg = gx * gy * gridDim.z;
        int flat = blockIdx.x + gx * (blockIdx.y + gy * blockIdx.z);
        int wg = (nwg & 7) ? flat : ((flat & 7) * (nwg >> 3) + (flat >> 3));
        bx = wg % gx;
        int tmp = wg / gx;
        by = tmp % gy;
        bz = tmp / gy;
    }

    const bf16_t* Az = A + (size_t)bz * sA;
    const bf16_t* Bz = B + (size_t)bz * sB;
    const int t = threadIdx.x;
    const int lane = t & 63, wid = t >> 6;
    const int wr = wid >> 2, wc = wid & 3;
    const int brow = by * 256, bcol = bx * 256;
    const int NT = K >> 6;

    const int r0 = t >> 3, s0 = t & 7;
    const int ce = ((s0 ^ (r0 & 7)) << 3);      // pre-swizzled source col (elems)
    const bf16_t* aP0 = Az + (size_t)(brow + r0) * K + ce;
    const bf16_t* bP0 = Bz + (size_t)(bcol + r0) * K + ce;
    const size_t rK64 = (size_t)64 * K;
    const size_t h128K = (size_t)128 * K;

    #define STAGE_A(kt_, h_) do { \
        bf16_t* d_ = AsL + ((((kt_) & 1) * 2 + (h_)) * 8192); \
        const bf16_t* s_ = aP0 + (size_t)(h_) * h128K + (size_t)(kt_) * 64; \
        async16(s_, d_ + t * 8); \
        async16(s_ + rK64, d_ + 4096 + t * 8); \
    } while (0)
    #define STAGE_B(kt_, h_) do { \
        bf16_t* d_ = BsL + ((((kt_) & 1) * 2 + (h_)) * 8192); \
        const bf16_t* s_ = bP0 + (size_t)(h_) * h128K + (size_t)(kt_) * 64; \
        async16(s_, d_ + t * 8); \
        async16(s_ + rK64, d_ + 4096 + t * 8); \
    } while (0)

    const int q = lane >> 4, rr0 = lane & 15, xmask = rr0 & 7;
    s16x8 af[4][2];
    s16x8 bv[2][2][2];
    f32x4 acc[2][2][4][2] = {};

    #define READ_A(ktp_, qm_) do { \
        const bf16_t* base_ = AsL + (((ktp_) * 2 + (qm_)) * 8192); \
        _Pragma("unroll") for (int m_ = 0; m_ < 4; ++m_) \
        _Pragma("unroll") for (int ks_ = 0; ks_ < 2; ++ks_) \
            af[m_][ks_] = *(const s16x8*)(base_ + (wr * 64 + m_ * 16 + rr0) * 64 + (((ks_ * 4 + q) ^ xmask) << 3)); \
    } while (0)
    #define READ_B(ktp_, qn_) do { \
        const bf16_t* base_ = BsL + (((ktp_) * 2 + (qn_)) * 8192); \
        _Pragma("unroll") for (int n_ = 0; n_ < 2; ++n_) \
        _Pragma("unroll") for (int ks_ = 0; ks_ < 2; ++ks_) \
            bv[qn_][n_][ks_] = *(const s16x8*)(base_ + (wc * 32 + n_ * 16 + rr0) * 64 + (((ks_ * 4 + q) ^ xmask) << 3)); \
    } while (0)
    #define MFMA_Q(qm_, qn_) do { \
        __builtin_amdgcn_s_setprio(1); \
        _Pragma("unroll") for (int m_ = 0; m_ < 4; ++m_) \
        _Pragma("unroll") for (int n_ = 0; n_ < 2; ++n_) \
        _Pragma("unroll") for (int ks_ = 0; ks_ < 2; ++ks_) \
            acc[qm_][qn_][m_][n_] = __builtin_amdgcn_mfma_f32_16x16x32_bf16( \
                af[m_][ks_], bv[qn_][n_][ks_], acc[qm_][qn_][m_][n_], 0, 0, 0); \
        __builtin_amdgcn_s_setprio(0); \
    } while (0)

    // ---- prologue: stage tile 0; A(0,1) may stay in flight ----
    STAGE_A(0, 0); STAGE_B(0, 0); STAGE_B(0, 1); STAGE_A(0, 1);
    asm volatile("s_waitcnt vmcnt(2)" ::: "memory");
    FULL_BAR();

    for (int kt = 0; kt < NT; ++kt) {
        const int ktp = kt & 1;
        // ---- phase 0: quadrants (0,0),(0,1) ----
        READ_A(ktp, 0);
        READ_B(ktp, 0);
        READ_B(ktp, 1);
        if (kt + 1 < NT) {
            STAGE_A(kt + 1, 0); STAGE_B(kt + 1, 0); STAGE_B(kt + 1, 1);
            asm volatile("s_waitcnt vmcnt(6)" ::: "memory");   // drains A(kt,1)
        } else {
            asm volatile("s_waitcnt vmcnt(0)" ::: "memory");
        }
        FULL_BAR();
        LGKM0();
        MFMA_Q(0, 0);
        MFMA_Q(0, 1);
        // ---- phase 1: quadrants (1,0),(1,1) ----
        READ_A(ktp, 1);
        if (kt + 1 < NT) {
            STAGE_A(kt + 1, 1);
            asm volatile("s_waitcnt vmcnt(2)" ::: "memory");   // drains next-tile A0/B0/B1
        }
        FULL_BAR();
        LGKM0();
        MFMA_Q(1, 0);
        MFMA_Q(1, 1);
    }

    // ---- epilogue: LDS-transposed coalesced stores ----
    // All staging LDS reads were completed (each wave's LGKM0 precedes its
    // final MFMAs which precede this barrier); vmcnt==0 at loop exit.
    FULL_BAR();
    size_t cz = (size_t)bz * sC;
    bf16_t (*Cl)[264] = (bf16_t(*)[264])lds;  // 128 rows x 264 (pad) = 66 KiB

    #pragma unroll
    for (int qm = 0; qm < 2; ++qm) {
        // -- write phase: shfl col-pairing, b32 LDS writes --
        #pragma unroll
        for (int qn = 0; qn < 2; ++qn) {
            #pragma unroll
            for (int n = 0; n < 2; ++n) {
                int col = qn * 128 + wc * 32 + n * 16 + rr0;   // within tile
                float bvv = (EPI == 1 || EPI == 4) ? bias[bcol + col] : 0.f;
                #pragma unroll
                for (int m = 0; m < 4; ++m) {
                    unsigned words[4];
                    #pragma unroll
                    for (int j = 0; j < 4; ++j) {
                        float v = acc[qm][qn][m][n][j] + bvv;
                        if constexpr (EPI == 1) v = fmaxf(v, 0.f);
                        if constexpr (EPI == 3) v *= alpha;
                        unsigned h = f2bf(v);
                        unsigned o = (unsigned)__shfl_xor((int)h, 1);
                        words[j] = (lane & 1) ? (o | (h << 16)) : (h | (o << 16));
                    }
                    int row = wr * 64 + m * 16 + q * 4 + (lane & 1) * 2;
                    int cp = col & ~1;
                    *(unsigned*)&Cl[row][cp]     = words[(lane & 1) * 2];
                    *(unsigned*)&Cl[row + 1][cp] = words[(lane & 1) * 2 + 1];
                }
            }
        }
        __syncthreads();
        // -- read phase: b128 LDS reads, dwordx4 global stores --
        int rrow = t >> 2;
        bf16_t* Crow = (bf16_t*)Cptr + cz + (size_t)(brow + qm * 128 + rrow) * Nc + bcol;
        #pragma unroll
        for (int s = 0; s < 8; ++s) {
            int segb = ((t & 3) + s * 4) * 8;       // col offset (8 bf16 = 16B)
            s16x8 vv = *(const s16x8*)&Cl[rrow][segb];
            *(s16x8*)(Crow + segb) = vv;
        }
        __syncthreads();
    }
    #undef STAGE_A
    #undef STAGE_B
    #undef READ_A
    #undef READ_B
    #undef MFMA_Q
}

// ---------------- softmax: bf16 scores (pre-scaled) in-place -> bf16 probs ---
__global__ __launch_bounds__(256) void softmax_bf16(
    bf16_t* __restrict__ S, const float* __restrict__ mask, int bc0) {
    __shared__ float sm[4];
    int gr = blockIdx.x;
    int b = (bc0 + (gr >> 11)) >> 2;
    bf16_t* row = S + (size_t)gr * CN;
    int tid = threadIdx.x;
    const float* mrow = mask + (size_t)b * CN + tid * 8;
    s16x8 v = *(const s16x8*)(row + tid * 8);
    float4 m0 = *(const float4*)(mrow);
    float4 m1 = *(const float4*)(mrow + 4);
    float x[8];
    x[0] = bf2f((unsigned short)v[0]) - m0.x * MASK_SCALE;
    x[1] = bf2f((unsigned short)v[1]) - m0.y * MASK_SCALE;
    x[2] = bf2f((unsigned short)v[2]) - m0.z * MASK_SCALE;
    x[3] = bf2f((unsigned short)v[3]) - m0.w * MASK_SCALE;
    x[4] = bf2f((unsigned short)v[4]) - m1.x * MASK_SCALE;
    x[5] = bf2f((unsigned short)v[5]) - m1.y * MASK_SCALE;
    x[6] = bf2f((unsigned short)v[6]) - m1.z * MASK_SCALE;
    x[7] = bf2f((unsigned short)v[7]) - m1.w * MASK_SCALE;
    float mx = -3.4e38f;
    #pragma unroll
    for (int i = 0; i < 8; i++) mx = fmaxf(mx, x[i]);
    mx = blockMax256(mx, sm);
    float s = 0.f;
    #pragma unroll
    for (int i = 0; i < 8; i++) { x[i] = __expf(x[i] - mx); s += x[i]; }
    s = blockSum256(s, sm);
    float inv = 1.f / s;
    s16x8 u;
    #pragma unroll
    for (int i = 0; i < 8; i++) u[i] = (short)f2bf(x[i] * inv);
    *(s16x8*)(row + tid * 8) = u;
}

// ---------------- residual + layernorm kernels (E=512, one block/row) --------
__global__ __launch_bounds__(256) void ln1_kernel(
    const bf16_t* __restrict__ src, const bf16_t* __restrict__ ao,
    const float* __restrict__ g, const float* __restrict__ be,
    bf16_t* __restrict__ o) {
    __shared__ float sm[4];
    size_t base = (size_t)blockIdx.x * CE;
    int e = threadIdx.x * 2;
    ushort2 s = *(const ushort2*)&src[base + e];
    ushort2 a = *(const ushort2*)&ao[base + e];
    float x0 = bf2f(s.x) + bf2f(a.x), x1 = bf2f(s.y) + bf2f(a.y);
    float mu = blockSum256(x0 + x1, sm) * (1.f / CE);
    float d0 = x0 - mu, d1 = x1 - mu;
    float var = blockSum256(d0 * d0 + d1 * d1, sm) * (1.f / CE);
    float rs = rsqrtf(var + EPS);
    ushort2 w;
    w.x = f2bf(d0 * rs * g[e] + be[e]);
    w.y = f2bf(d1 * rs * g[e + 1] + be[e + 1]);
    *(ushort2*)&o[base + e] = w;
}

__global__ __launch_bounds__(256) void ln2_kernel(
    const bf16_t* __restrict__ a, const bf16_t* __restrict__ b,
    const float* __restrict__ g, const float* __restrict__ be,
    float* __restrict__ o) {
    __shared__ float sm[4];
    size_t base = (size_t)blockIdx.x * CE;
    int e = threadIdx.x * 2;
    ushort2 aa = *(const ushort2*)&a[base + e];
    ushort2 bb = *(const ushort2*)&b[base + e];
    float x0 = bf2f(aa.x) + bf2f(bb.x), x1 = bf2f(aa.y) + bf2f(bb.y);
    float mu = blockSum256(x0 + x1, sm) * (1.f / CE);
    float d0 = x0 - mu, d1 = x1 - mu;
    float var = blockSum256(d0 * d0 + d1 * d1, sm) * (1.f / CE);
    float rs = rsqrtf(var + EPS);
    float2 w;
    w.x = d0 * rs * g[e] + be[e];
    w.y = d1 * rs * g[e + 1] + be[e + 1];
    *(float2*)&o[base + e] = w;
}

// ---------------- host ----------------
extern "C" void kernel_launch(void* const* d_in, const int* in_sizes, int n_in,
                              void* d_out, int out_size, void* d_ws, size_t ws_size,
                              hipStream_t stream) {
    const float* src  = (const float*)d_in[0];
    const float* mask = (const float*)d_in[1];
    const float* W1   = (const float*)d_in[2];
    const float* b1   = (const float*)d_in[3];
    const float* W2   = (const float*)d_in[4];
    const float* b2   = (const float*)d_in[5];
    const float* g1   = (const float*)d_in[6];
    const float* be1  = (const float*)d_in[7];
    const float* g2   = (const float*)d_in[8];
    const float* be2  = (const float*)d_in[9];
    float* out = (float*)d_out;
    char* ws = (char*)d_ws;

    hipFuncSetAttribute(reinterpret_cast<const void*>(&gemm256<1>), hipFuncAttributeMaxDynamicSharedMemorySize, 131072);
    hipFuncSetAttribute(reinterpret_cast<const void*>(&gemm256<3>), hipFuncAttributeMaxDynamicSharedMemorySize, 131072);
    hipFuncSetAttribute(reinterpret_cast<const void*>(&gemm256<4>), hipFuncAttributeMaxDynamicSharedMemorySize, 131072);

    // ---- workspace layout (MiB offsets) ----
    // [0,256)   scores/probs bf16 (all 32)  | FFN: [0,64)=src2, [64,128)=ff, [128,384)=H
    // [256,320) src_bf
    // [320,384) srcT
    // [384,448) attnO (bf16)
    // [448,452) W1T, W2T
    const size_t MB = 1024 * 1024;
    bf16_t* probs  = (bf16_t*)(ws);              // scores in-place -> probs
    bf16_t* src_bf = (bf16_t*)(ws + 256 * MB);
    bf16_t* srcT   = (bf16_t*)(ws + 320 * MB);
    bf16_t* attnO  = (bf16_t*)(ws + 384 * MB);
    bf16_t* W1T    = (bf16_t*)(ws + 448 * MB);
    bf16_t* W2T    = (bf16_t*)(ws + 450 * MB);
    bf16_t* src2   = (bf16_t*)(ws);              // overlays probs (dead after PV)
    bf16_t* ff     = (bf16_t*)(ws + 64 * MB);    // overlays probs
    bf16_t* H      = (bf16_t*)(ws + 128 * MB);   // overlays probs tail
    if (ws_size < 452 * MB) return;

    // ---- conversions ----
    cvt_f32_bf16_vec<<<4096, 256, 0, stream>>>(src, src_bf, TOT);
    transpose_f32_bf16<<<dim3(CF / 32, CE / 32, 1), 256, 0, stream>>>(W1, W1T, CE, CF);
    transpose_f32_bf16<<<dim3(CE / 32, CF / 32, 1), 256, 0, stream>>>(W2, W2T, CF, CE);
    transpose_bf16<<<dim3(CE / 32, CN / 32, 32), 256, 0, stream>>>(
        src_bf, srcT, CN, CE, (long long)CN * CE, (long long)CE * CN);

    // ---- attention in LLC-resident groups: scores -> softmax -> PV ----
    for (int g0 = 0; g0 < CB * CC; g0 += GRP) {
        const bf16_t* srcb = src_bf + (size_t)g0 * CN * CE;
        bf16_t* probs_g = probs + (size_t)g0 * CN * CN;
        gemm256<3><<<dim3(CN / 256, CN / 256, GRP), 512, 131072, stream>>>(
            srcb, srcb, probs_g, nullptr, SCALE, CN, CN, CE,
            (long long)CN * CE, (long long)CN * CE, (long long)CN * CN);
        softmax_bf16<<<dim3(GRP * CN), 256, 0, stream>>>(probs_g, mask, g0);
        gemm256<3><<<dim3(CE / 256, CN / 256, GRP), 512, 131072, stream>>>(
            probs_g, srcT + (size_t)g0 * CE * CN, attnO + (size_t)g0 * CN * CE,
            nullptr, 1.0f, CN, CE, CN,
            (long long)CN * CN, (long long)CE * CN, (long long)CN * CE);
    }
    ln1_kernel<<<dim3(CB * CC * CN), 256, 0, stream>>>(src_bf, attnO, g1, be1, src2);

    // ---- FFN + final LN (single chunk) ----
    gemm256<1><<<dim3(CF / 256, MCH / 256, 1), 512, 131072, stream>>>(
        src2, W1T, H, b1, 1.0f, MCH, CF, CE, 0, 0, 0);
    gemm256<4><<<dim3(CE / 256, MCH / 256, 1), 512, 131072, stream>>>(
        H, W2T, ff, b2, 1.0f, MCH, CE, CF, 0, 0, 0);
    ln2_kernel<<<dim3(MCH), 256, 0, stream>>>(src2, ff, g2, be2, out);
}

// Round 6
// 912.680 us; speedup vs baseline: 1.0397x; 1.0397x over previous
//
#include <hip/hip_runtime.h>
#include <stdint.h>

// ---------------- problem constants ----------------
constexpr int CB = 8, CC = 4, CN = 2048, CE = 512, CF = 2048;
constexpr long long TOT = (long long)CB * CC * CN * CE;
constexpr int GRP = 16;       // attention batches per LLC-resident group
constexpr int MCH = 65536;    // FFN rows (single chunk)
constexpr float SCALE = 0.04419417382415922f;  // 1/sqrt(512)
constexpr float MASK_SCALE = 5.0f;
constexpr float EPS = 1e-5f;

typedef unsigned short bf16_t;
typedef __attribute__((ext_vector_type(4))) float f32x4;
typedef __attribute__((ext_vector_type(8))) short s16x8;

#define DEV static __device__ __forceinline__

DEV unsigned short f2bf(float f) {
    unsigned u = __float_as_uint(f);
    unsigned r = (u + 0x7fffu + ((u >> 16) & 1u)) >> 16;
    return (unsigned short)r;
}
DEV float bf2f(unsigned short b) {
    return __uint_as_float(((unsigned)b) << 16);
}

typedef const __attribute__((address_space(1))) unsigned int* gptr_t;
typedef __attribute__((address_space(3))) unsigned int* lptr_t;
DEV void async16(const void* g, void* l) {
    __builtin_amdgcn_global_load_lds((gptr_t)g, (lptr_t)l, 16, 0, 0);
}

#define FULL_BAR() do { asm volatile("" ::: "memory"); __builtin_amdgcn_s_barrier(); asm volatile("" ::: "memory"); } while (0)
#define LGKM0() asm volatile("s_waitcnt lgkmcnt(0)" ::: "memory")
#define SCHED0() __builtin_amdgcn_sched_barrier(0)
#define VMCNT(N_) asm volatile("s_waitcnt vmcnt(" #N_ ")" ::: "memory")

// ---------------- reductions (256-thread blocks = 4 waves) ----------------
DEV float blockSum256(float v, float* sm) {
    #pragma unroll
    for (int o = 32; o; o >>= 1) v += __shfl_xor(v, o);
    int w = threadIdx.x >> 6;
    __syncthreads();
    if ((threadIdx.x & 63) == 0) sm[w] = v;
    __syncthreads();
    return sm[0] + sm[1] + sm[2] + sm[3];
}
DEV float blockMax256(float v, float* sm) {
    #pragma unroll
    for (int o = 32; o; o >>= 1) v = fmaxf(v, __shfl_xor(v, o));
    int w = threadIdx.x >> 6;
    __syncthreads();
    if ((threadIdx.x & 63) == 0) sm[w] = v;
    __syncthreads();
    return fmaxf(fmaxf(sm[0], sm[1]), fmaxf(sm[2], sm[3]));
}

// ---------------- fp32 -> bf16 convert ----------------
__global__ __launch_bounds__(256) void cvt_f32_bf16_vec(
    const float* __restrict__ in, bf16_t* __restrict__ out, long long n) {
    long long i = ((long long)blockIdx.x * 256 + threadIdx.x) * 4;
    long long stride = (long long)gridDim.x * 1024;
    for (; i < n; i += stride) {
        float4 v = *reinterpret_cast<const float4*>(in + i);
        ushort4 u;
        u.x = f2bf(v.x); u.y = f2bf(v.y); u.z = f2bf(v.z); u.w = f2bf(v.w);
        *reinterpret_cast<ushort4*>(out + i) = u;
    }
}

// ---------------- transpose fp32[R][C] -> bf16[C][R] (weights) ----------------
__global__ __launch_bounds__(256) void transpose_f32_bf16(
    const float* __restrict__ in, bf16_t* __restrict__ out,
    int R, int Cc) {
    __shared__ float tile[32][33];
    int rb = blockIdx.y * 32, cb = blockIdx.x * 32;
    int tx = threadIdx.x & 31, ty = threadIdx.x >> 5;
    #pragma unroll
    for (int i = 0; i < 32; i += 8)
        tile[ty + i][tx] = in[(size_t)(rb + ty + i) * Cc + cb + tx];
    __syncthreads();
    #pragma unroll
    for (int i = 0; i < 32; i += 8)
        out[(size_t)(cb + ty + i) * R + rb + tx] = f2bf(tile[tx][ty + i]);
}

// ---------------- transpose bf16[R][C] -> bf16[C][R], batched via z ----------------
__global__ __launch_bounds__(256) void transpose_bf16(
    const bf16_t* __restrict__ in, bf16_t* __restrict__ out,
    int R, int Cc, long long sIn, long long sOut) {
    __shared__ bf16_t tile[32][36];
    const bf16_t* inz = in + (size_t)blockIdx.z * sIn;
    bf16_t* outz = out + (size_t)blockIdx.z * sOut;
    int rb = blockIdx.y * 32, cb = blockIdx.x * 32;
    int t = threadIdx.x;
    int r = t >> 3, c4 = (t & 7) * 4;
    *(ushort4*)&tile[r][c4] = *(const ushort4*)&inz[(size_t)(rb + r) * Cc + cb + c4];
    __syncthreads();
    int c = t >> 3, r4 = (t & 7) * 4;
    ushort4 w;
    w.x = tile[r4 + 0][c]; w.y = tile[r4 + 1][c];
    w.z = tile[r4 + 2][c]; w.w = tile[r4 + 3][c];
    *(ushort4*)&outz[(size_t)(cb + c) * R + rb + r4] = w;
}

// ============ persistent 256x256 GEMM: C[M,Nc] = A[M,K] @ B[Nc,K]^T ============
// bf16 in, fp32 acc. 8 waves (2Mx4N), BK=64, 128KiB LDS double-buffered.
// 4 phases/K-tile (16 MFMA each); 1 half-tile push per phase in FIFO order
// {A0,B0,B1,A1}; vmcnt(4) drains at ages >=2 phases. Persistent blocks:
// grid=256, pushes roll across output tiles with an unchanged ledger.
// Tile order: bx fastest, bz, by slowest -> per-block tile sequence keeps the
// same B panel (and batch) L2-resident.
// EPI 1: +bias relu bf16. 3: alpha*bf16. 4: +bias bf16.
template <int EPI>
__global__ __launch_bounds__(512, 2) void gemm256(
    const bf16_t* __restrict__ A, const bf16_t* __restrict__ B,
    void* __restrict__ Cptr, const float* __restrict__ bias, float alpha,
    int Nc, int K, long long sA, long long sB, long long sC,
    int gx, int gz, int nTiles) {
    extern __shared__ bf16_t lds[];
    bf16_t* AsL = lds;           // [dbuf2][half2][64rows*64k]
    bf16_t* BsL = lds + 32768;
    const int t = threadIdx.x;
    const int lane = t & 63, wid = t >> 6;
    const int wr = wid >> 2, wc = wid & 3;
    const int NT = K >> 6;

    const int r0 = t >> 3, s0 = t & 7;
    const int ce = ((s0 ^ (r0 & 7)) << 3);      // pre-swizzled source col
    const size_t rK64 = (size_t)64 * K;
    const size_t h128K = rK64 * 2;

    #define PUSH_A(src_, p_, h_) do { \
        bf16_t* d_ = AsL + (((p_) * 2 + (h_)) * 8192); \
        const bf16_t* s_ = (src_) + (size_t)(h_) * h128K; \
        async16(s_, d_ + t * 8); \
        async16(s_ + rK64, d_ + 4096 + t * 8); \
    } while (0)
    #define PUSH_B(src_, p_, h_) do { \
        bf16_t* d_ = BsL + (((p_) * 2 + (h_)) * 8192); \
        const bf16_t* s_ = (src_) + (size_t)(h_) * h128K; \
        async16(s_, d_ + t * 8); \
        async16(s_ + rK64, d_ + 4096 + t * 8); \
    } while (0)

    const int q = lane >> 4, rr0 = lane & 15, xmask = rr0 & 7;
    s16x8 af[4][2];
    s16x8 bv[2][2][2];

    #define READ_A(ktp_, qm_) do { \
        const bf16_t* base_ = AsL + (((ktp_) * 2 + (qm_)) * 8192); \
        _Pragma("unroll") for (int m_ = 0; m_ < 4; ++m_) \
        _Pragma("unroll") for (int ks_ = 0; ks_ < 2; ++ks_) \
            af[m_][ks_] = *(const s16x8*)(base_ + (wr * 64 + m_ * 16 + rr0) * 64 + (((ks_ * 4 + q) ^ xmask) << 3)); \
    } while (0)
    #define READ_B(ktp_, qn_) do { \
        const bf16_t* base_ = BsL + (((ktp_) * 2 + (qn_)) * 8192); \
        _Pragma("unroll") for (int n_ = 0; n_ < 2; ++n_) \
        _Pragma("unroll") for (int ks_ = 0; ks_ < 2; ++ks_) \
            bv[qn_][n_][ks_] = *(const s16x8*)(base_ + (wc * 32 + n_ * 16 + rr0) * 64 + (((ks_ * 4 + q) ^ xmask) << 3)); \
    } while (0)
    #define MFMA_Q(qm_, qn_) do { \
        __builtin_amdgcn_s_setprio(1); \
        _Pragma("unroll") for (int m_ = 0; m_ < 4; ++m_) \
        _Pragma("unroll") for (int n_ = 0; n_ < 2; ++n_) \
        _Pragma("unroll") for (int ks_ = 0; ks_ < 2; ++ks_) \
            acc[qm_][qn_][m_][n_] = __builtin_amdgcn_mfma_f32_16x16x32_bf16( \
                af[m_][ks_], bv[qn_][n_][ks_], acc[qm_][qn_][m_][n_], 0, 0, 0); \
        __builtin_amdgcn_s_setprio(0); \
    } while (0)

    int tile = blockIdx.x;
    if (tile >= nTiles) return;
    int bx, by, bz, nbx = 0, nby = 0, nbz = 0;
    const bf16_t *aPc, *bPc, *aPn = nullptr, *bPn = nullptr;

    // decode: bx fastest, then bz, then by (B panel reuse across a block's tiles)
    {
        bx = tile % gx; int r = tile / gx; bz = r % gz; by = r / gz;
        aPc = A + (size_t)bz * sA + (size_t)(by * 256 + r0) * K + ce;
        bPc = B + (size_t)bz * sB + (size_t)(bx * 256 + r0) * K + ce;
    }

    // prologue: push kt0 halves in FIFO order {A0,B0,B1,A1}; drain A0,B0
    PUSH_A(aPc, 0, 0); PUSH_B(bPc, 0, 0); PUSH_B(bPc, 0, 1); PUSH_A(aPc, 0, 1);
    VMCNT(4);
    FULL_BAR();

    while (true) {
        int ntile = tile + (int)gridDim.x;
        bool have_next = ntile < nTiles;
        if (have_next) {
            nbx = ntile % gx; int r = ntile / gx; nbz = r % gz; nby = r / gz;
            aPn = A + (size_t)nbz * sA + (size_t)(nby * 256 + r0) * K + ce;
            bPn = B + (size_t)nbz * sB + (size_t)(nbx * 256 + r0) * K + ce;
        } else { aPn = aPc; bPn = bPc; }

        f32x4 acc[2][2][4][2] = {};

        for (int kt = 0; kt < NT; ++kt) {
            const int ktp = kt & 1;
            const int sp = (kt + 1) & 1;
            const bool more = (kt + 1 < NT) || have_next;
            const bf16_t* aS = (kt + 1 < NT) ? aPc + (size_t)(kt + 1) * 64 : aPn;
            const bf16_t* bS = (kt + 1 < NT) ? bPc + (size_t)(kt + 1) * 64 : bPn;

            // ---- ph00: quadrant (0,0) ----
            READ_A(ktp, 0);
            READ_B(ktp, 0);
            if (more) { PUSH_A(aS, sp, 0); VMCNT(4); } else { VMCNT(2); }
            FULL_BAR(); LGKM0(); SCHED0();
            MFMA_Q(0, 0);
            // ---- ph01: quadrant (0,1) ----
            READ_B(ktp, 1);
            if (more) { PUSH_B(bS, sp, 0); VMCNT(4); } else { VMCNT(0); }
            FULL_BAR(); LGKM0(); SCHED0();
            MFMA_Q(0, 1);
            // ---- ph10: quadrant (1,0) ----
            READ_A(ktp, 1);
            if (more) { PUSH_B(bS, sp, 1); }
            FULL_BAR(); LGKM0(); SCHED0();
            MFMA_Q(1, 0);
            // ---- ph11: quadrant (1,1) ----
            if (more) { PUSH_A(aS, sp, 1); VMCNT(4); }
            FULL_BAR();
            MFMA_Q(1, 1);
        }

        // ---- epilogue: shfl col-pairing -> dword stores (no LDS use) ----
        {
            size_t cz = (size_t)bz * sC;
            bf16_t* Cb = (bf16_t*)Cptr + cz;
            const int brow = by * 256, bcol = bx * 256;
            const int lo = lane & 1;
            #pragma unroll
            for (int qm = 0; qm < 2; ++qm)
            #pragma unroll
            for (int qn = 0; qn < 2; ++qn)
            #pragma unroll
            for (int n = 0; n < 2; ++n) {
                int col = bcol + qn * 128 + wc * 32 + n * 16 + rr0;
                float bvv = (EPI == 1 || EPI == 4) ? bias[col] : 0.f;
                #pragma unroll
                for (int m = 0; m < 4; ++m) {
                    unsigned words[4];
                    #pragma unroll
                    for (int j = 0; j < 4; ++j) {
                        float v = acc[qm][qn][m][n][j] + bvv;
                        if constexpr (EPI == 1) v = fmaxf(v, 0.f);
                        if constexpr (EPI == 3) v *= alpha;
                        unsigned h = f2bf(v);
                        unsigned o = (unsigned)__shfl_xor((int)h, 1);
                        words[j] = lo ? (o | (h << 16)) : (h | (o << 16));
                    }
                    int row = brow + qm * 128 + wr * 64 + m * 16 + q * 4 + lo * 2;
                    int cp = col & ~1;
                    *(unsigned*)&Cb[(size_t)row * Nc + cp] = words[lo * 2];
                    *(unsigned*)&Cb[(size_t)(row + 1) * Nc + cp] = words[lo * 2 + 1];
                }
            }
        }

        if (!have_next) break;
        tile = ntile; bx = nbx; by = nby; bz = nbz; aPc = aPn; bPc = bPn;
    }
    #undef PUSH_A
    #undef PUSH_B
    #undef READ_A
    #undef READ_B
    #undef MFMA_Q
}

// ---------------- softmax: bf16 scores (pre-scaled) in-place -> bf16 probs ---
__global__ __launch_bounds__(256) void softmax_bf16(
    bf16_t* __restrict__ S, const float* __restrict__ mask, int bc0) {
    __shared__ float sm[4];
    int gr = blockIdx.x;
    int b = (bc0 + (gr >> 11)) >> 2;
    bf16_t* row = S + (size_t)gr * CN;
    int tid = threadIdx.x;
    const float* mrow = mask + (size_t)b * CN + tid * 8;
    s16x8 v = *(const s16x8*)(row + tid * 8);
    float4 m0 = *(const float4*)(mrow);
    float4 m1 = *(const float4*)(mrow + 4);
    float x[8];
    x[0] = bf2f((unsigned short)v[0]) - m0.x * MASK_SCALE;
    x[1] = bf2f((unsigned short)v[1]) - m0.y * MASK_SCALE;
    x[2] = bf2f((unsigned short)v[2]) - m0.z * MASK_SCALE;
    x[3] = bf2f((unsigned short)v[3]) - m0.w * MASK_SCALE;
    x[4] = bf2f((unsigned short)v[4]) - m1.x * MASK_SCALE;
    x[5] = bf2f((unsigned short)v[5]) - m1.y * MASK_SCALE;
    x[6] = bf2f((unsigned short)v[6]) - m1.z * MASK_SCALE;
    x[7] = bf2f((unsigned short)v[7]) - m1.w * MASK_SCALE;
    float mx = -3.4e38f;
    #pragma unroll
    for (int i = 0; i < 8; i++) mx = fmaxf(mx, x[i]);
    mx = blockMax256(mx, sm);
    float s = 0.f;
    #pragma unroll
    for (int i = 0; i < 8; i++) { x[i] = __expf(x[i] - mx); s += x[i]; }
    s = blockSum256(s, sm);
    float inv = 1.f / s;
    s16x8 u;
    #pragma unroll
    for (int i = 0; i < 8; i++) u[i] = (short)f2bf(x[i] * inv);
    *(s16x8*)(row + tid * 8) = u;
}

// ---------------- residual + layernorm kernels (E=512, one block/row) --------
__global__ __launch_bounds__(256) void ln1_kernel(
    const bf16_t* __restrict__ src, const bf16_t* __restrict__ ao,
    const float* __restrict__ g, const float* __restrict__ be,
    bf16_t* __restrict__ o) {
    __shared__ float sm[4];
    size_t base = (size_t)blockIdx.x * CE;
    int e = threadIdx.x * 2;
    ushort2 s = *(const ushort2*)&src[base + e];
    ushort2 a = *(const ushort2*)&ao[base + e];
    float x0 = bf2f(s.x) + bf2f(a.x), x1 = bf2f(s.y) + bf2f(a.y);
    float mu = blockSum256(x0 + x1, sm) * (1.f / CE);
    float d0 = x0 - mu, d1 = x1 - mu;
    float var = blockSum256(d0 * d0 + d1 * d1, sm) * (1.f / CE);
    float rs = rsqrtf(var + EPS);
    ushort2 w;
    w.x = f2bf(d0 * rs * g[e] + be[e]);
    w.y = f2bf(d1 * rs * g[e + 1] + be[e + 1]);
    *(ushort2*)&o[base + e] = w;
}

__global__ __launch_bounds__(256) void ln2_kernel(
    const bf16_t* __restrict__ a, const bf16_t* __restrict__ b,
    const float* __restrict__ g, const float* __restrict__ be,
    float* __restrict__ o) {
    __shared__ float sm[4];
    size_t base = (size_t)blockIdx.x * CE;
    int e = threadIdx.x * 2;
    ushort2 aa = *(const ushort2*)&a[base + e];
    ushort2 bb = *(const ushort2*)&b[base + e];
    float x0 = bf2f(aa.x) + bf2f(bb.x), x1 = bf2f(aa.y) + bf2f(bb.y);
    float mu = blockSum256(x0 + x1, sm) * (1.f / CE);
    float d0 = x0 - mu, d1 = x1 - mu;
    float var = blockSum256(d0 * d0 + d1 * d1, sm) * (1.f / CE);
    float rs = rsqrtf(var + EPS);
    float2 w;
    w.x = d0 * rs * g[e] + be[e];
    w.y = d1 * rs * g[e + 1] + be[e + 1];
    *(float2*)&o[base + e] = w;
}

// ---------------- host ----------------
extern "C" void kernel_launch(void* const* d_in, const int* in_sizes, int n_in,
                              void* d_out, int out_size, void* d_ws, size_t ws_size,
                              hipStream_t stream) {
    const float* src  = (const float*)d_in[0];
    const float* mask = (const float*)d_in[1];
    const float* W1   = (const float*)d_in[2];
    const float* b1   = (const float*)d_in[3];
    const float* W2   = (const float*)d_in[4];
    const float* b2   = (const float*)d_in[5];
    const float* g1   = (const float*)d_in[6];
    const float* be1  = (const float*)d_in[7];
    const float* g2   = (const float*)d_in[8];
    const float* be2  = (const float*)d_in[9];
    float* out = (float*)d_out;
    char* ws = (char*)d_ws;

    hipFuncSetAttribute(reinterpret_cast<const void*>(&gemm256<1>), hipFuncAttributeMaxDynamicSharedMemorySize, 131072);
    hipFuncSetAttribute(reinterpret_cast<const void*>(&gemm256<3>), hipFuncAttributeMaxDynamicSharedMemorySize, 131072);
    hipFuncSetAttribute(reinterpret_cast<const void*>(&gemm256<4>), hipFuncAttributeMaxDynamicSharedMemorySize, 131072);

    // ---- workspace layout (MiB offsets) ----
    // [0,256)   scores/probs bf16 (all 32)  | FFN: [0,64)=src2, [64,128)=ff, [128,384)=H
    // [256,320) src_bf
    // [320,384) srcT
    // [384,448) attnO (bf16)
    // [448,452) W1T, W2T
    const size_t MB = 1024 * 1024;
    bf16_t* probs  = (bf16_t*)(ws);              // scores in-place -> probs
    bf16_t* src_bf = (bf16_t*)(ws + 256 * MB);
    bf16_t* srcT   = (bf16_t*)(ws + 320 * MB);
    bf16_t* attnO  = (bf16_t*)(ws + 384 * MB);
    bf16_t* W1T    = (bf16_t*)(ws + 448 * MB);
    bf16_t* W2T    = (bf16_t*)(ws + 450 * MB);
    bf16_t* src2   = (bf16_t*)(ws);              // overlays probs (dead after PV)
    bf16_t* ff     = (bf16_t*)(ws + 64 * MB);    // overlays probs
    bf16_t* H      = (bf16_t*)(ws + 128 * MB);   // overlays probs tail
    if (ws_size < 452 * MB) return;

    // ---- conversions ----
    cvt_f32_bf16_vec<<<4096, 256, 0, stream>>>(src, src_bf, TOT);
    transpose_f32_bf16<<<dim3(CF / 32, CE / 32, 1), 256, 0, stream>>>(W1, W1T, CE, CF);
    transpose_f32_bf16<<<dim3(CE / 32, CF / 32, 1), 256, 0, stream>>>(W2, W2T, CF, CE);
    transpose_bf16<<<dim3(CE / 32, CN / 32, 32), 256, 0, stream>>>(
        src_bf, srcT, CN, CE, (long long)CN * CE, (long long)CE * CN);

    // ---- attention in LLC-resident groups: scores -> softmax -> PV ----
    for (int g0 = 0; g0 < CB * CC; g0 += GRP) {
        const bf16_t* srcb = src_bf + (size_t)g0 * CN * CE;
        bf16_t* probs_g = probs + (size_t)g0 * CN * CN;
        gemm256<3><<<256, 512, 131072, stream>>>(
            srcb, srcb, probs_g, nullptr, SCALE, CN, CE,
            (long long)CN * CE, (long long)CN * CE, (long long)CN * CN,
            CN / 256, GRP, (CN / 256) * (CN / 256) * GRP);
        softmax_bf16<<<dim3(GRP * CN), 256, 0, stream>>>(probs_g, mask, g0);
        gemm256<3><<<256, 512, 131072, stream>>>(
            probs_g, srcT + (size_t)g0 * CE * CN, attnO + (size_t)g0 * CN * CE,
            nullptr, 1.0f, CE, CN,
            (long long)CN * CN, (long long)CE * CN, (long long)CN * CE,
            CE / 256, GRP, (CE / 256) * (CN / 256) * GRP);
    }
    ln1_kernel<<<dim3(CB * CC * CN), 256, 0, stream>>>(src_bf, attnO, g1, be1, src2);

    // ---- FFN + final LN (single chunk) ----
    gemm256<1><<<256, 512, 131072, stream>>>(
        src2, W1T, H, b1, 1.0f, CF, CE, 0, 0, 0,
        CF / 256, 1, (CF / 256) * (MCH / 256));
    gemm256<4><<<256, 512, 131072, stream>>>(
        H, W2T, ff, b2, 1.0f, CE, CF, 0, 0, 0,
        CE / 256, 1, (CE / 256) * (MCH / 256));
    ln2_kernel<<<dim3(MCH), 256, 0, stream>>>(src2, ff, g2, be2, out);
}

// Round 7
// 903.286 us; speedup vs baseline: 1.0505x; 1.0104x over previous
//
#include <hip/hip_runtime.h>
#include <stdint.h>

// ---------------- problem constants ----------------
constexpr int CB = 8, CC = 4, CN = 2048, CE = 512, CF = 2048;
constexpr long long TOT = (long long)CB * CC * CN * CE;
constexpr int GRP = 16;       // attention batches per LLC-resident group
constexpr int MCH = 65536;    // FFN rows (single chunk)
constexpr float SCALE = 0.04419417382415922f;  // 1/sqrt(512)
constexpr float MASK_SCALE = 5.0f;
constexpr float EPS = 1e-5f;

typedef unsigned short bf16_t;
typedef __attribute__((ext_vector_type(4))) float f32x4;
typedef __attribute__((ext_vector_type(8))) short s16x8;

#define DEV static __device__ __forceinline__

DEV unsigned short f2bf(float f) {
    unsigned u = __float_as_uint(f);
    unsigned r = (u + 0x7fffu + ((u >> 16) & 1u)) >> 16;
    return (unsigned short)r;
}
DEV float bf2f(unsigned short b) {
    return __uint_as_float(((unsigned)b) << 16);
}

typedef const __attribute__((address_space(1))) unsigned int* gptr_t;
typedef __attribute__((address_space(3))) unsigned int* lptr_t;
DEV void async16(const void* g, void* l) {
    __builtin_amdgcn_global_load_lds((gptr_t)g, (lptr_t)l, 16, 0, 0);
}

#define FULL_BAR() do { asm volatile("" ::: "memory"); __builtin_amdgcn_s_barrier(); asm volatile("" ::: "memory"); } while (0)
#define LGKM0() asm volatile("s_waitcnt lgkmcnt(0)" ::: "memory")
#define LGKM8() asm volatile("s_waitcnt lgkmcnt(8)" ::: "memory")
#define SCHED0() __builtin_amdgcn_sched_barrier(0)
#define VMCNT(N_) asm volatile("s_waitcnt vmcnt(" #N_ ")" ::: "memory")

// ---------------- reductions (256-thread blocks = 4 waves) ----------------
DEV float blockSum256(float v, float* sm) {
    #pragma unroll
    for (int o = 32; o; o >>= 1) v += __shfl_xor(v, o);
    int w = threadIdx.x >> 6;
    __syncthreads();
    if ((threadIdx.x & 63) == 0) sm[w] = v;
    __syncthreads();
    return sm[0] + sm[1] + sm[2] + sm[3];
}
DEV float blockMax256(float v, float* sm) {
    #pragma unroll
    for (int o = 32; o; o >>= 1) v = fmaxf(v, __shfl_xor(v, o));
    int w = threadIdx.x >> 6;
    __syncthreads();
    if ((threadIdx.x & 63) == 0) sm[w] = v;
    __syncthreads();
    return fmaxf(fmaxf(sm[0], sm[1]), fmaxf(sm[2], sm[3]));
}

// ---------------- fp32 -> bf16 convert ----------------
__global__ __launch_bounds__(256) void cvt_f32_bf16_vec(
    const float* __restrict__ in, bf16_t* __restrict__ out, long long n) {
    long long i = ((long long)blockIdx.x * 256 + threadIdx.x) * 4;
    long long stride = (long long)gridDim.x * 1024;
    for (; i < n; i += stride) {
        float4 v = *reinterpret_cast<const float4*>(in + i);
        ushort4 u;
        u.x = f2bf(v.x); u.y = f2bf(v.y); u.z = f2bf(v.z); u.w = f2bf(v.w);
        *reinterpret_cast<ushort4*>(out + i) = u;
    }
}

// ---------------- transpose fp32[R][C] -> bf16[C][R] (weights) ----------------
__global__ __launch_bounds__(256) void transpose_f32_bf16(
    const float* __restrict__ in, bf16_t* __restrict__ out,
    int R, int Cc) {
    __shared__ float tile[32][33];
    int rb = blockIdx.y * 32, cb = blockIdx.x * 32;
    int tx = threadIdx.x & 31, ty = threadIdx.x >> 5;
    #pragma unroll
    for (int i = 0; i < 32; i += 8)
        tile[ty + i][tx] = in[(size_t)(rb + ty + i) * Cc + cb + tx];
    __syncthreads();
    #pragma unroll
    for (int i = 0; i < 32; i += 8)
        out[(size_t)(cb + ty + i) * R + rb + tx] = f2bf(tile[tx][ty + i]);
}

// ---------------- transpose bf16[R][C] -> bf16[C][R], batched via z ----------------
__global__ __launch_bounds__(256) void transpose_bf16(
    const bf16_t* __restrict__ in, bf16_t* __restrict__ out,
    int R, int Cc, long long sIn, long long sOut) {
    __shared__ bf16_t tile[32][36];
    const bf16_t* inz = in + (size_t)blockIdx.z * sIn;
    bf16_t* outz = out + (size_t)blockIdx.z * sOut;
    int rb = blockIdx.y * 32, cb = blockIdx.x * 32;
    int t = threadIdx.x;
    int r = t >> 3, c4 = (t & 7) * 4;
    *(ushort4*)&tile[r][c4] = *(const ushort4*)&inz[(size_t)(rb + r) * Cc + cb + c4];
    __syncthreads();
    int c = t >> 3, r4 = (t & 7) * 4;
    ushort4 w;
    w.x = tile[r4 + 0][c]; w.y = tile[r4 + 1][c];
    w.z = tile[r4 + 2][c]; w.w = tile[r4 + 3][c];
    *(ushort4*)&outz[(size_t)(cb + c) * R + rb + r4] = w;
}

// ============ 256x256 GEMM, m201 8-phase schedule: C = A[M,K] @ B[Nc,K]^T ====
// bf16 in, fp32 acc. 8 waves (2Mx4N), BK=64, 128KiB LDS double-buffered.
// 4 phases per K-tile, TWO barriers per phase (reads+push | BAR | lgkm0 |
// MFMA 16 | BAR). Push pipeline 4 phases deep: P1 pushes A1(T+1), P2-P4 push
// A0/B0/B1(T+2). vmcnt(6) ONLY at P4 (drains all of tile T+1, pushed >=3
// phases earlier); vmcnt(0) only in the 2-tile tail. Race audit: every LDS
// overwrite is >=2 barriers after the lgkm0-completed reads of its prior data.
// XOR swizzle on 16B k-slots; XCD-aware bijective block swizzle (nwg%8==0).
// EPI 1: +bias relu bf16. 3: alpha*bf16. 4: +bias bf16.
template <int EPI>
__global__ __launch_bounds__(512, 2) void gemm256(
    const bf16_t* __restrict__ A, const bf16_t* __restrict__ B,
    void* __restrict__ Cptr, const float* __restrict__ bias, float alpha,
    int Nc, int K, long long sA, long long sB, long long sC) {
    extern __shared__ bf16_t lds[];
    bf16_t* AsL = lds;           // [dbuf2][half2][64rows*64k]
    bf16_t* BsL = lds + 32768;

    // ---- XCD-aware bijective swizzle (requires nwg % 8 == 0) ----
    int bx, by, bz;
    {
        int gx = gridDim.x, gy = gridDim.y;
        int nwg = gx * gy * gridDim.z;
        int flat = blockIdx.x + gx * (blockIdx.y + gy * blockIdx.z);
        int wg = (nwg & 7) ? flat : ((flat & 7) * (nwg >> 3) + (flat >> 3));
        bx = wg % gx;
        int tmp = wg / gx;
        by = tmp % gy;
        bz = tmp / gy;
    }

    const bf16_t* Az = A + (size_t)bz * sA;
    const bf16_t* Bz = B + (size_t)bz * sB;
    const int t = threadIdx.x;
    const int lane = t & 63, wid = t >> 6;
    const int wr = wid >> 2, wc = wid & 3;
    const int brow = by * 256, bcol = bx * 256;
    const int NT = K >> 6;

    const int r0 = t >> 3, s0 = t & 7;
    const int ce = ((s0 ^ (r0 & 7)) << 3);      // pre-swizzled source col
    const bf16_t* aP0 = Az + (size_t)(brow + r0) * K + ce;
    const bf16_t* bP0 = Bz + (size_t)(bcol + r0) * K + ce;
    const size_t rK64 = (size_t)64 * K;
    const size_t h128K = rK64 * 2;

    #define PUSH_A(kt_, h_) do { \
        bf16_t* d_ = AsL + ((((kt_) & 1) * 2 + (h_)) * 8192); \
        const bf16_t* s_ = aP0 + (size_t)(h_) * h128K + (size_t)(kt_) * 64; \
        async16(s_, d_ + t * 8); \
        async16(s_ + rK64, d_ + 4096 + t * 8); \
    } while (0)
    #define PUSH_B(kt_, h_) do { \
        bf16_t* d_ = BsL + ((((kt_) & 1) * 2 + (h_)) * 8192); \
        const bf16_t* s_ = bP0 + (size_t)(h_) * h128K + (size_t)(kt_) * 64; \
        async16(s_, d_ + t * 8); \
        async16(s_ + rK64, d_ + 4096 + t * 8); \
    } while (0)

    const int q = lane >> 4, rr0 = lane & 15, xmask = rr0 & 7;
    s16x8 af[4][2];
    s16x8 bv[2][2][2];
    f32x4 acc[2][2][4][2] = {};

    #define READ_A(ktp_, qm_) do { \
        const bf16_t* base_ = AsL + (((ktp_) * 2 + (qm_)) * 8192); \
        _Pragma("unroll") for (int m_ = 0; m_ < 4; ++m_) \
        _Pragma("unroll") for (int ks_ = 0; ks_ < 2; ++ks_) \
            af[m_][ks_] = *(const s16x8*)(base_ + (wr * 64 + m_ * 16 + rr0) * 64 + (((ks_ * 4 + q) ^ xmask) << 3)); \
    } while (0)
    #define READ_B(ktp_, qn_) do { \
        const bf16_t* base_ = BsL + (((ktp_) * 2 + (qn_)) * 8192); \
        _Pragma("unroll") for (int n_ = 0; n_ < 2; ++n_) \
        _Pragma("unroll") for (int ks_ = 0; ks_ < 2; ++ks_) \
            bv[qn_][n_][ks_] = *(const s16x8*)(base_ + (wc * 32 + n_ * 16 + rr0) * 64 + (((ks_ * 4 + q) ^ xmask) << 3)); \
    } while (0)
    #define MFMA_Q(qm_, qn_) do { \
        __builtin_amdgcn_s_setprio(1); \
        _Pragma("unroll") for (int m_ = 0; m_ < 4; ++m_) \
        _Pragma("unroll") for (int n_ = 0; n_ < 2; ++n_) \
        _Pragma("unroll") for (int ks_ = 0; ks_ < 2; ++ks_) \
            acc[qm_][qn_][m_][n_] = __builtin_amdgcn_mfma_f32_16x16x32_bf16( \
                af[m_][ks_], bv[qn_][n_][ks_], acc[qm_][qn_][m_][n_], 0, 0, 0); \
        __builtin_amdgcn_s_setprio(0); \
    } while (0)

    // ---- prologue (NT >= 8 always): tile0 fully landed, tile1 3 halves in flight
    PUSH_A(0, 0); PUSH_B(0, 0); PUSH_B(0, 1); PUSH_A(0, 1);
    VMCNT(4);                       // A0(0),B0(0) landed
    PUSH_A(1, 0); PUSH_B(1, 0); PUSH_B(1, 1);
    VMCNT(6);                       // B1(0),A1(0) landed -> tile0 complete
    FULL_BAR();

    for (int T = 0; T < NT; ++T) {
        const int p = T & 1;
        const bool m1 = (T + 1 < NT), m2 = (T + 2 < NT);
        // ---- P1: quadrant (0,0) ----
        READ_A(p, 0);
        READ_B(p, 0);
        if (m1) PUSH_A(T + 1, 1);
        LGKM8();
        FULL_BAR(); LGKM0(); SCHED0();
        MFMA_Q(0, 0);
        FULL_BAR();
        // ---- P2: quadrant (0,1) ----
        READ_B(p, 1);
        if (m2) PUSH_A(T + 2, 0);
        FULL_BAR(); LGKM0(); SCHED0();
        MFMA_Q(0, 1);
        FULL_BAR();
        // ---- P3: quadrant (1,0) ----
        READ_A(p, 1);
        if (m2) PUSH_B(T + 2, 0);
        FULL_BAR(); LGKM0(); SCHED0();
        MFMA_Q(1, 0);
        FULL_BAR();
        // ---- P4: quadrant (1,1) ----
        if (m2) { PUSH_B(T + 2, 1); VMCNT(6); } else { VMCNT(0); }
        FULL_BAR();
        MFMA_Q(1, 1);
        FULL_BAR();
    }

    // ---- epilogue: shfl col-pairing -> dword stores ----
    {
        size_t cz = (size_t)bz * sC;
        bf16_t* Cb = (bf16_t*)Cptr + cz;
        const int lo = lane & 1;
        #pragma unroll
        for (int qm = 0; qm < 2; ++qm)
        #pragma unroll
        for (int qn = 0; qn < 2; ++qn)
        #pragma unroll
        for (int n = 0; n < 2; ++n) {
            int col = bcol + qn * 128 + wc * 32 + n * 16 + rr0;
            float bvv = (EPI == 1 || EPI == 4) ? bias[col] : 0.f;
            #pragma unroll
            for (int m = 0; m < 4; ++m) {
                unsigned words[4];
                #pragma unroll
                for (int j = 0; j < 4; ++j) {
                    float v = acc[qm][qn][m][n][j] + bvv;
                    if constexpr (EPI == 1) v = fmaxf(v, 0.f);
                    if constexpr (EPI == 3) v *= alpha;
                    unsigned h = f2bf(v);
                    unsigned o = (unsigned)__shfl_xor((int)h, 1);
                    words[j] = lo ? (o | (h << 16)) : (h | (o << 16));
                }
                int row = brow + qm * 128 + wr * 64 + m * 16 + q * 4 + lo * 2;
                int cp = col & ~1;
                *(unsigned*)&Cb[(size_t)row * Nc + cp] = words[lo * 2];
                *(unsigned*)&Cb[(size_t)(row + 1) * Nc + cp] = words[lo * 2 + 1];
            }
        }
    }
    #undef PUSH_A
    #undef PUSH_B
    #undef READ_A
    #undef READ_B
    #undef MFMA_Q
}

// ---------------- softmax: bf16 scores (pre-scaled) in-place -> bf16 probs ---
__global__ __launch_bounds__(256) void softmax_bf16(
    bf16_t* __restrict__ S, const float* __restrict__ mask, int bc0) {
    __shared__ float sm[4];
    int gr = blockIdx.x;
    int b = (bc0 + (gr >> 11)) >> 2;
    bf16_t* row = S + (size_t)gr * CN;
    int tid = threadIdx.x;
    const float* mrow = mask + (size_t)b * CN + tid * 8;
    s16x8 v = *(const s16x8*)(row + tid * 8);
    float4 m0 = *(const float4*)(mrow);
    float4 m1 = *(const float4*)(mrow + 4);
    float x[8];
    x[0] = bf2f((unsigned short)v[0]) - m0.x * MASK_SCALE;
    x[1] = bf2f((unsigned short)v[1]) - m0.y * MASK_SCALE;
    x[2] = bf2f((unsigned short)v[2]) - m0.z * MASK_SCALE;
    x[3] = bf2f((unsigned short)v[3]) - m0.w * MASK_SCALE;
    x[4] = bf2f((unsigned short)v[4]) - m1.x * MASK_SCALE;
    x[5] = bf2f((unsigned short)v[5]) - m1.y * MASK_SCALE;
    x[6] = bf2f((unsigned short)v[6]) - m1.z * MASK_SCALE;
    x[7] = bf2f((unsigned short)v[7]) - m1.w * MASK_SCALE;
    float mx = -3.4e38f;
    #pragma unroll
    for (int i = 0; i < 8; i++) mx = fmaxf(mx, x[i]);
    mx = blockMax256(mx, sm);
    float s = 0.f;
    #pragma unroll
    for (int i = 0; i < 8; i++) { x[i] = __expf(x[i] - mx); s += x[i]; }
    s = blockSum256(s, sm);
    float inv = 1.f / s;
    s16x8 u;
    #pragma unroll
    for (int i = 0; i < 8; i++) u[i] = (short)f2bf(x[i] * inv);
    *(s16x8*)(row + tid * 8) = u;
}

// ---------------- residual + layernorm kernels (E=512, one block/row) --------
__global__ __launch_bounds__(256) void ln1_kernel(
    const bf16_t* __restrict__ src, const bf16_t* __restrict__ ao,
    const float* __restrict__ g, const float* __restrict__ be,
    bf16_t* __restrict__ o) {
    __shared__ float sm[4];
    size_t base = (size_t)blockIdx.x * CE;
    int e = threadIdx.x * 2;
    ushort2 s = *(const ushort2*)&src[base + e];
    ushort2 a = *(const ushort2*)&ao[base + e];
    float x0 = bf2f(s.x) + bf2f(a.x), x1 = bf2f(s.y) + bf2f(a.y);
    float mu = blockSum256(x0 + x1, sm) * (1.f / CE);
    float d0 = x0 - mu, d1 = x1 - mu;
    float var = blockSum256(d0 * d0 + d1 * d1, sm) * (1.f / CE);
    float rs = rsqrtf(var + EPS);
    ushort2 w;
    w.x = f2bf(d0 * rs * g[e] + be[e]);
    w.y = f2bf(d1 * rs * g[e + 1] + be[e + 1]);
    *(ushort2*)&o[base + e] = w;
}

__global__ __launch_bounds__(256) void ln2_kernel(
    const bf16_t* __restrict__ a, const bf16_t* __restrict__ b,
    const float* __restrict__ g, const float* __restrict__ be,
    float* __restrict__ o) {
    __shared__ float sm[4];
    size_t base = (size_t)blockIdx.x * CE;
    int e = threadIdx.x * 2;
    ushort2 aa = *(const ushort2*)&a[base + e];
    ushort2 bb = *(const ushort2*)&b[base + e];
    float x0 = bf2f(aa.x) + bf2f(bb.x), x1 = bf2f(aa.y) + bf2f(bb.y);
    float mu = blockSum256(x0 + x1, sm) * (1.f / CE);
    float d0 = x0 - mu, d1 = x1 - mu;
    float var = blockSum256(d0 * d0 + d1 * d1, sm) * (1.f / CE);
    float rs = rsqrtf(var + EPS);
    float2 w;
    w.x = d0 * rs * g[e] + be[e];
    w.y = d1 * rs * g[e + 1] + be[e + 1];
    *(float2*)&o[base + e] = w;
}

// ---------------- host ----------------
extern "C" void kernel_launch(void* const* d_in, const int* in_sizes, int n_in,
                              void* d_out, int out_size, void* d_ws, size_t ws_size,
                              hipStream_t stream) {
    const float* src  = (const float*)d_in[0];
    const float* mask = (const float*)d_in[1];
    const float* W1   = (const float*)d_in[2];
    const float* b1   = (const float*)d_in[3];
    const float* W2   = (const float*)d_in[4];
    const float* b2   = (const float*)d_in[5];
    const float* g1   = (const float*)d_in[6];
    const float* be1  = (const float*)d_in[7];
    const float* g2   = (const float*)d_in[8];
    const float* be2  = (const float*)d_in[9];
    float* out = (float*)d_out;
    char* ws = (char*)d_ws;

    hipFuncSetAttribute(reinterpret_cast<const void*>(&gemm256<1>), hipFuncAttributeMaxDynamicSharedMemorySize, 131072);
    hipFuncSetAttribute(reinterpret_cast<const void*>(&gemm256<3>), hipFuncAttributeMaxDynamicSharedMemorySize, 131072);
    hipFuncSetAttribute(reinterpret_cast<const void*>(&gemm256<4>), hipFuncAttributeMaxDynamicSharedMemorySize, 131072);

    // ---- workspace layout (MiB offsets) ----
    // [0,256)   scores/probs bf16 (all 32)  | FFN: [0,64)=src2, [64,128)=ff, [128,384)=H
    // [256,320) src_bf
    // [320,384) srcT
    // [384,448) attnO (bf16)
    // [448,452) W1T, W2T
    const size_t MB = 1024 * 1024;
    bf16_t* probs  = (bf16_t*)(ws);              // scores in-place -> probs
    bf16_t* src_bf = (bf16_t*)(ws + 256 * MB);
    bf16_t* srcT   = (bf16_t*)(ws + 320 * MB);
    bf16_t* attnO  = (bf16_t*)(ws + 384 * MB);
    bf16_t* W1T    = (bf16_t*)(ws + 448 * MB);
    bf16_t* W2T    = (bf16_t*)(ws + 450 * MB);
    bf16_t* src2   = (bf16_t*)(ws);              // overlays probs (dead after PV)
    bf16_t* ff     = (bf16_t*)(ws + 64 * MB);    // overlays probs
    bf16_t* H      = (bf16_t*)(ws + 128 * MB);   // overlays probs tail
    if (ws_size < 452 * MB) return;

    // ---- conversions ----
    cvt_f32_bf16_vec<<<4096, 256, 0, stream>>>(src, src_bf, TOT);
    transpose_f32_bf16<<<dim3(CF / 32, CE / 32, 1), 256, 0, stream>>>(W1, W1T, CE, CF);
    transpose_f32_bf16<<<dim3(CE / 32, CF / 32, 1), 256, 0, stream>>>(W2, W2T, CF, CE);
    transpose_bf16<<<dim3(CE / 32, CN / 32, 32), 256, 0, stream>>>(
        src_bf, srcT, CN, CE, (long long)CN * CE, (long long)CE * CN);

    // ---- attention in LLC-resident groups: scores -> softmax -> PV ----
    for (int g0 = 0; g0 < CB * CC; g0 += GRP) {
        const bf16_t* srcb = src_bf + (size_t)g0 * CN * CE;
        bf16_t* probs_g = probs + (size_t)g0 * CN * CN;
        gemm256<3><<<dim3(CN / 256, CN / 256, GRP), 512, 131072, stream>>>(
            srcb, srcb, probs_g, nullptr, SCALE, CN, CE,
            (long long)CN * CE, (long long)CN * CE, (long long)CN * CN);
        softmax_bf16<<<dim3(GRP * CN), 256, 0, stream>>>(probs_g, mask, g0);
        gemm256<3><<<dim3(CE / 256, CN / 256, GRP), 512, 131072, stream>>>(
            probs_g, srcT + (size_t)g0 * CE * CN, attnO + (size_t)g0 * CN * CE,
            nullptr, 1.0f, CE, CN,
            (long long)CN * CN, (long long)CE * CN, (long long)CN * CE);
    }
    ln1_kernel<<<dim3(CB * CC * CN), 256, 0, stream>>>(src_bf, attnO, g1, be1, src2);

    // ---- FFN + final LN (single chunk) ----
    gemm256<1><<<dim3(CF / 256, MCH / 256, 1), 512, 131072, stream>>>(
        src2, W1T, H, b1, 1.0f, CF, CE, 0, 0, 0);
    gemm256<4><<<dim3(CE / 256, MCH / 256, 1), 512, 131072, stream>>>(
        H, W2T, ff, b2, 1.0f, CE, CF, 0, 0, 0);
    ln2_kernel<<<dim3(MCH), 256, 0, stream>>>(src2, ff, g2, be2, out);
}